// Round 3
// baseline (402.929 us; speedup 1.0000x reference)
//
#include <hip/hip_runtime.h>
#include <cstdint>

// CrossAttentionFusion: seq_len=1 cross-attention => softmax==1 => attention is
// identity on V. Whole net collapses to:
//   W1 = w_o1 @ wv1 ; b1 = w_o1 @ bv1 + b_o1   (wv1 = w_qkv1[2d:3d,:])
//   z  = [x_u @ W1^T + b1 , x_m @ W2^T + b2]   [B, 2d]
//   out = gelu( LN(z; g,b) @ w_proj^T + b_proj )
// LN folded into proj epilogue: h = rstd*(z.Wp'^T - mu*S) + C.
// R5: R4's dual-barrier phase split REVERTED (regressed 94->102: compiler
// already overlaps ds_read->MFMA via per-use lgkmcnt; extra barriers were pure
// cost). New lever: cross-block TLP. Big GEMM reshaped 256x256/8wave/1blk-CU
// -> 256x128/4wave with 3-slot ring (72 KiB LDS) => 2 blocks/CU. Counted
// vmcnt kept: stage t+2 during t, end-of-tile vmcnt(6), taper to 0.

#define DIM 1024
#define BROWS 16384

typedef __bf16 bf16x8 __attribute__((ext_vector_type(8)));
typedef float f32x4 __attribute__((ext_vector_type(4)));

__device__ __forceinline__ ushort f2bf(float f) {
    uint32_t u = __builtin_bit_cast(uint32_t, f);
    u = (u + 0x7fffu + ((u >> 16) & 1u)) >> 16;
    return (ushort)u;
}

// global -> LDS direct copy, 16B per lane. LDS dest is wave-uniform base;
// HW writes lane i at base + i*16.
__device__ __forceinline__ void async_copy16(const void* gsrc, void* ldst) {
    __builtin_amdgcn_global_load_lds(
        (__attribute__((address_space(1))) void*)((uintptr_t)gsrc),
        (__attribute__((address_space(3))) void*)((uint32_t)(uintptr_t)ldst),
        16, 0, 0);
}

// ---------------- merged prep kernel (unchanged) ----------------
__global__ __launch_bounds__(256) void prep_kernel(
        const float* __restrict__ x_u, const float* __restrict__ x_m,
        const float* __restrict__ wqkv1, const float* __restrict__ bqkv1,
        const float* __restrict__ wo1, const float* __restrict__ bo1,
        const float* __restrict__ wqkv2, const float* __restrict__ bqkv2,
        const float* __restrict__ wo2, const float* __restrict__ bo2,
        const float* __restrict__ lng, const float* __restrict__ lnb,
        const float* __restrict__ wproj, const float* __restrict__ bproj,
        ushort* __restrict__ x_bf, ushort* __restrict__ wo12,
        ushort* __restrict__ wvT12, ushort* __restrict__ Wp,
        float* __restrict__ b12, float* __restrict__ Svec, float* __restrict__ Cvec,
        float* __restrict__ sums) {
    const int b = blockIdx.x, t = threadIdx.x;
    __shared__ float red[4][4];
    __shared__ float tls[32][33];

    if (b < 8192) {
        const int n4 = (BROWS * DIM) / 4;
        int i = b * 256 + t;
        const int stride = 8192 * 256;
        const float4* xu4 = (const float4*)x_u;
        const float4* xm4 = (const float4*)x_m;
        ushort4* o4 = (ushort4*)x_bf;
#pragma unroll
        for (int it = 0; it < 4; it++, i += stride) {
            float4 v = (i < n4) ? xu4[i] : xm4[i - n4];
            ushort4 o;
            o.x = f2bf(v.x); o.y = f2bf(v.y); o.z = f2bf(v.z); o.w = f2bf(v.w);
            o4[i] = o;
        }
    } else if (b < 9216) {
        int j = b - 8192;
        float s1 = 0.f, s2 = 0.f, sS = 0.f, sC = 0.f;
        for (int c = t; c < DIM; c += 256) {
            s1 += wo1[j * DIM + c] * bqkv1[2 * DIM + c];
            s2 += wo2[j * DIM + c] * bqkv2[2 * DIM + c];
        }
        for (int c = t; c < 2 * DIM; c += 256) {
            float w = wproj[j * 2 * DIM + c];
            sS += w * lng[c];
            sC += w * lnb[c];
        }
        for (int o = 32; o; o >>= 1) {
            s1 += __shfl_down(s1, o, 64);
            s2 += __shfl_down(s2, o, 64);
            sS += __shfl_down(sS, o, 64);
            sC += __shfl_down(sC, o, 64);
        }
        int wid = t >> 6;
        if ((t & 63) == 0) { red[wid][0] = s1; red[wid][1] = s2; red[wid][2] = sS; red[wid][3] = sC; }
        __syncthreads();
        if (t == 0) {
            s1 = red[0][0] + red[1][0] + red[2][0] + red[3][0];
            s2 = red[0][1] + red[1][1] + red[2][1] + red[3][1];
            sS = red[0][2] + red[1][2] + red[2][2] + red[3][2];
            sC = red[0][3] + red[1][3] + red[2][3] + red[3][3];
            b12[j]       = s1 + bo1[j];
            b12[DIM + j] = s2 + bo2[j];
            Svec[j] = sS;
            Cvec[j] = sC + bproj[j];
        }
    } else if (b < 12288) {
        const int NWO = (DIM * DIM) / 4;
        const int NWP = (DIM * 2 * DIM) / 4;
        const int total = 2 * NWO + NWP;
        int i = (b - 9216) * 256 + t;
        const int stride = 3072 * 256;
        for (; i < total; i += stride) {
            if (i < 2 * NWO) {
                float4 v = (i < NWO) ? ((const float4*)wo1)[i] : ((const float4*)wo2)[i - NWO];
                ushort4 o;
                o.x = f2bf(v.x); o.y = f2bf(v.y); o.z = f2bf(v.z); o.w = f2bf(v.w);
                ((ushort4*)wo12)[i] = o;
            } else {
                int j = i - 2 * NWO;
                float4 v = ((const float4*)wproj)[j];
                int c = (j * 4) & (2 * DIM - 1);
                v.x *= lng[c]; v.y *= lng[c + 1]; v.z *= lng[c + 2]; v.w *= lng[c + 3];
                ushort4 o;
                o.x = f2bf(v.x); o.y = f2bf(v.y); o.z = f2bf(v.z); o.w = f2bf(v.w);
                ((ushort4*)Wp)[j] = o;
            }
        }
    } else if (b < 14336) {
        int tile = b - 12288;
        int z = tile >> 10;
        int t2 = tile & 1023;
        int mt = t2 >> 5, kt = t2 & 31;
        const float* src = z ? wqkv2 : wqkv1;
        int tr = t >> 3;
        int tc4 = (t & 7) * 4;
        const float* p = src + (long)(2 * DIM + mt * 32 + tr) * DIM + kt * 32 + tc4;
        float4 v = *(const float4*)p;
        tls[tr][tc4 + 0] = v.x; tls[tr][tc4 + 1] = v.y;
        tls[tr][tc4 + 2] = v.z; tls[tr][tc4 + 3] = v.w;
        __syncthreads();
        ushort4 o;
        o.x = f2bf(tls[tc4 + 0][tr]);
        o.y = f2bf(tls[tc4 + 1][tr]);
        o.z = f2bf(tls[tc4 + 2][tr]);
        o.w = f2bf(tls[tc4 + 3][tr]);
        *(ushort4*)(wvT12 + (long)z * DIM * DIM + (long)(kt * 32 + tr) * DIM + mt * 32 + tc4) = o;
    } else {
        int i = (b - 14336) * 256 + t;
        ((float4*)sums)[i] = float4{0.f, 0.f, 0.f, 0.f};
    }
}

// ---------------- small weight GEMM (64x64, unchanged) ----------
__global__ __launch_bounds__(256, 2) void gemm_w(
        const ushort* __restrict__ Ag, const ushort* __restrict__ Wg,
        ushort* __restrict__ Cg, int K, int lda, int ldw, int ldc,
        long sAz, long sWz, long sCz) {
    constexpr int BM = 64, BN = 64, BK = 32;
    constexpr int MT = BM / 32;
    constexpr int NT = BN / 32;
    __shared__ __align__(16) ushort As[BM * BK];
    __shared__ __align__(16) ushort Bs[BN * BK];
    const int tid = threadIdx.x;
    const int wid = tid >> 6;
    const int lane = tid & 63;
    const int quad = lane >> 4;
    const int l16 = lane & 15;
    const int waveM = wid >> 1, waveN = wid & 1;
    const int zb = blockIdx.z;

    const ushort* A = Ag + zb * sAz + (long)blockIdx.x * BM * lda;
    const ushort* W = Wg + zb * sWz + (long)blockIdx.y * BN * ldw;

    f32x4 acc[MT][NT] = {};
    constexpr int nA = (BM * BK) / (256 * 8);
    constexpr int nB = (BN * BK) / (256 * 8);
    const int swz = (l16 >> 1) & 3;
    const int rdA = quad ^ swz;
    for (int k0 = 0; k0 < K; k0 += BK) {
#pragma unroll
        for (int c = 0; c < nA; c++) {
            int idx = c * 256 + tid;
            int r = idx >> 2;
            int q = (idx & 3) ^ ((r >> 1) & 3);
            async_copy16(A + (long)r * lda + k0 + q * 8, (char*)As + (c * 256 + wid * 64) * 16);
        }
#pragma unroll
        for (int c = 0; c < nB; c++) {
            int idx = c * 256 + tid;
            int r = idx >> 2;
            int q = (idx & 3) ^ ((r >> 1) & 3);
            async_copy16(W + (long)r * ldw + k0 + q * 8, (char*)Bs + (c * 256 + wid * 64) * 16);
        }
        asm volatile("s_waitcnt vmcnt(0)" ::: "memory");
        __syncthreads();

        bf16x8 af[MT], bfg[NT];
#pragma unroll
        for (int im = 0; im < MT; im++)
            af[im] = *(const bf16x8*)(As + (waveM * (BM / 2) + im * 16 + l16) * BK + rdA * 8);
#pragma unroll
        for (int in = 0; in < NT; in++)
            bfg[in] = *(const bf16x8*)(Bs + (waveN * (BN / 2) + in * 16 + l16) * BK + rdA * 8);
#pragma unroll
        for (int im = 0; im < MT; im++)
#pragma unroll
            for (int in = 0; in < NT; in++)
                acc[im][in] = __builtin_amdgcn_mfma_f32_16x16x32_bf16(
                    af[im], bfg[in], acc[im][in], 0, 0, 0);
        __syncthreads();
    }

    const int gRow0 = blockIdx.x * BM + waveM * (BM / 2) + quad * 4;
    const int gCol0 = blockIdx.y * BN + waveN * (BN / 2) + l16;
    ushort* C = Cg + zb * sCz;
#pragma unroll
    for (int im = 0; im < MT; im++)
#pragma unroll
        for (int in = 0; in < NT; in++) {
            int col = gCol0 + in * 16;
#pragma unroll
            for (int r = 0; r < 4; r++) {
                int row = gRow0 + im * 16 + r;
                C[(long)row * ldc + col] = f2bf(acc[im][in][r]);
            }
        }
}

// ---------------- big GEMM: 256x128 tile, 4 waves, 3-slot ring, 2 blocks/CU --
// MODE 1: C bf16 = acc + bias[zb*DIM+col]; fused LN-stats atomics
// MODE 2: C fp32 = gelu(rstd*(acc - mu*S) + Cv)
//
// Ring ledger (3 slots, distance-2 prefetch):
//  - tile t in slot t%3; during tile t stage tile t+2 into slot (t+2)%3
//    (never the slot being read (t) nor the next one (t+1)).
//  - each wave issues 6 copies/tile (4 A-rounds + 2 B-rounds).
//  - end of tile t: t<NTK-2 -> vmcnt(6) (t+2's copies may fly, t+1
//    guaranteed); t==NTK-2 -> vmcnt(0); t==NTK-1 -> no wait.
//  - single s_barrier per tile (R3 body: compiler's per-use lgkmcnt already
//    overlaps ds_read service with early MFMAs).
template <int MODE>
__global__ __launch_bounds__(256, 2) void gemm_bt2(
        const ushort* __restrict__ Ag, const ushort* __restrict__ Wg,
        void* __restrict__ Cg, int K, int lda, int ldw, int ldc,
        long sAz, long sWz, long sCz,
        const float* __restrict__ bias,
        const float* __restrict__ Svec, const float* __restrict__ Cvec,
        float* __restrict__ sumbuf, float* __restrict__ sqbuf) {
    __shared__ __align__(16) ushort As[3 * 8192];   // 3 slots x [256][32] bf16 = 48 KiB
    __shared__ __align__(16) ushort Bs[3 * 4096];   // 3 slots x [128][32] bf16 = 24 KiB
    const int tid = threadIdx.x;
    const int wid = tid >> 6;
    const int lane = tid & 63;
    const int quad = lane >> 4;
    const int l16 = lane & 15;
    const int waveM = wid >> 1;   // 0..1 -> 128 rows each
    const int waveN = wid & 1;    // 0..1 -> 64 cols each
    const int zb = blockIdx.z;
    const int rd = quad ^ ((l16 >> 1) & 3);   // XOR chunk swizzle (0 conflicts)

    const ushort* A = Ag + zb * sAz + (long)blockIdx.x * 256 * lda;
    const ushort* W = Wg + zb * sWz + (long)blockIdx.y * 128 * ldw;
    const int NTK = K >> 5;

    f32x4 acc[8][4] = {};

    // ---- prologue: stage tiles 0,1 (12 copies/wave), guarantee tile 0 ----
#pragma unroll
    for (int u = 0; u < 2; ++u) {
        const int k0 = u << 5;
        char* sa = (char*)As + u * 16384;
        char* sb = (char*)Bs + u * 8192;
#pragma unroll
        for (int rnd = 0; rnd < 4; ++rnd) {
            int idx = rnd * 256 + tid;
            int r = idx >> 2;
            int q = (idx & 3) ^ ((r >> 1) & 3);
            async_copy16(A + (long)r * lda + k0 + q * 8, sa + (rnd * 256 + wid * 64) * 16);
        }
#pragma unroll
        for (int rnd = 0; rnd < 2; ++rnd) {
            int idx = rnd * 256 + tid;
            int r = idx >> 2;
            int q = (idx & 3) ^ ((r >> 1) & 3);
            async_copy16(W + (long)r * ldw + k0 + q * 8, sb + (rnd * 256 + wid * 64) * 16);
        }
    }
    asm volatile("s_waitcnt vmcnt(6)" ::: "memory");
    __builtin_amdgcn_s_barrier();
    asm volatile("" ::: "memory");

    int cs = 0, ss = 2;   // current slot, stage slot ((t+2)%3)
    for (int t = 0; t < NTK; ++t) {
        const ushort* as = As + cs * 8192;
        const ushort* bs = Bs + cs * 4096;

        bf16x8 af[8], bfg[4];
#pragma unroll
        for (int j = 0; j < 4; ++j)
            bfg[j] = *(const bf16x8*)(bs + (waveN * 64 + j * 16 + l16) * 32 + rd * 8);
#pragma unroll
        for (int i = 0; i < 8; ++i)
            af[i] = *(const bf16x8*)(as + (waveM * 128 + i * 16 + l16) * 32 + rd * 8);

        const int u = t + 2;
        if (u < NTK) {
            const int k0u = u << 5;
            char* sa = (char*)As + ss * 16384;
            char* sb = (char*)Bs + ss * 8192;
#pragma unroll
            for (int rnd = 0; rnd < 4; ++rnd) {
                int idx = rnd * 256 + tid;
                int r = idx >> 2;
                int q = (idx & 3) ^ ((r >> 1) & 3);
                async_copy16(A + (long)r * lda + k0u + q * 8, sa + (rnd * 256 + wid * 64) * 16);
            }
#pragma unroll
            for (int rnd = 0; rnd < 2; ++rnd) {
                int idx = rnd * 256 + tid;
                int r = idx >> 2;
                int q = (idx & 3) ^ ((r >> 1) & 3);
                async_copy16(W + (long)r * ldw + k0u + q * 8, sb + (rnd * 256 + wid * 64) * 16);
            }
        }

        __builtin_amdgcn_s_setprio(1);
#pragma unroll
        for (int i = 0; i < 8; ++i)
#pragma unroll
            for (int j = 0; j < 4; ++j)
                acc[i][j] = __builtin_amdgcn_mfma_f32_16x16x32_bf16(
                    af[i], bfg[j], acc[i][j], 0, 0, 0);
        __builtin_amdgcn_s_setprio(0);

        if (t < NTK - 1) {
            if (t < NTK - 2) asm volatile("s_waitcnt vmcnt(6)" ::: "memory");
            else             asm volatile("s_waitcnt vmcnt(0)" ::: "memory");
            __builtin_amdgcn_s_barrier();
            asm volatile("" ::: "memory");
        }
        cs = (cs == 2) ? 0 : cs + 1;
        ss = (ss == 2) ? 0 : ss + 1;
    }

    // ---- epilogue: C/D layout col=lane&15, row=quad*4+reg ----
    const int gRow0 = blockIdx.x * 256 + waveM * 128 + quad * 4;
    const int gCol0 = blockIdx.y * 128 + waveN * 64 + l16;
    if constexpr (MODE == 1) {
        ushort* C = (ushort*)Cg + zb * sCz;
#pragma unroll
        for (int im = 0; im < 8; ++im) {
            float sr[4] = {0.f, 0.f, 0.f, 0.f};
            float qr[4] = {0.f, 0.f, 0.f, 0.f};
#pragma unroll
            for (int in = 0; in < 4; ++in) {
                int col = gCol0 + in * 16;
                float badd = bias[zb * DIM + col];
#pragma unroll
                for (int r = 0; r < 4; ++r) {
                    int row = gRow0 + im * 16 + r;
                    float val = acc[im][in][r] + badd;
                    C[(long)row * ldc + col] = f2bf(val);
                    sr[r] += val;
                    qr[r] += val * val;
                }
            }
#pragma unroll
            for (int r = 0; r < 4; ++r) {
                float s = sr[r], q = qr[r];
#pragma unroll
                for (int o = 1; o < 16; o <<= 1) {
                    s += __shfl_xor(s, o, 64);
                    q += __shfl_xor(q, o, 64);
                }
                if (l16 == 0) {
                    int row = gRow0 + im * 16 + r;
                    atomicAdd(&sumbuf[row], s);
                    atomicAdd(&sqbuf[row], q);
                }
            }
        }
    } else {
        float* O = (float*)Cg;
#pragma unroll
        for (int im = 0; im < 8; ++im) {
#pragma unroll
            for (int r = 0; r < 4; ++r) {
                int row = gRow0 + im * 16 + r;
                float sv = sumbuf[row], qv = sqbuf[row];
                float m = sv * (1.f / 2048.f);
                float var = qv * (1.f / 2048.f) - m * m;
                float rstd = rsqrtf(var + 1e-5f);
#pragma unroll
                for (int in = 0; in < 4; ++in) {
                    int col = gCol0 + in * 16;
                    float h = rstd * (acc[im][in][r] - m * Svec[col]) + Cvec[col];
                    O[(long)row * ldc + col] = 0.5f * h * (1.0f + erff(h * 0.7071067811865475f));
                }
            }
        }
    }
}

// ---------------- launch ----------------

extern "C" void kernel_launch(void* const* d_in, const int* in_sizes, int n_in,
                              void* d_out, int out_size, void* d_ws, size_t ws_size,
                              hipStream_t stream) {
    (void)in_sizes; (void)n_in; (void)out_size; (void)ws_size;
    const float* x_u   = (const float*)d_in[0];
    const float* x_m   = (const float*)d_in[1];
    const float* wqkv1 = (const float*)d_in[2];
    const float* bqkv1 = (const float*)d_in[3];
    const float* wo1   = (const float*)d_in[4];
    const float* bo1   = (const float*)d_in[5];
    const float* wqkv2 = (const float*)d_in[6];
    const float* bqkv2 = (const float*)d_in[7];
    const float* wo2   = (const float*)d_in[8];
    const float* bo2   = (const float*)d_in[9];
    const float* lng   = (const float*)d_in[10];
    const float* lnb   = (const float*)d_in[11];
    const float* wproj = (const float*)d_in[12];
    const float* bproj = (const float*)d_in[13];

    char* ws = (char*)d_ws;
    ushort* x_bf  = (ushort*)(ws + 0);          // [2][B][D] bf16: 67,108,864 B
    ushort* wo12  = (ushort*)(ws + 67108864);   // [2][D][D]: 4 MB
    ushort* wvT12 = (ushort*)(ws + 71303168);   // [2][D][D]: 4 MB
    ushort* W12   = (ushort*)(ws + 75497472);   // [2][D][D]: 4 MB
    ushort* Wp    = (ushort*)(ws + 79691776);   // [D][2D]: 4 MB
    ushort* zbuf  = (ushort*)(ws + 83886080);   // [B][2D]: 67,108,864 B
    float*  b12   = (float*)(ws + 150994944);   // [2][D]
    float*  Svec  = (float*)(ws + 151003136);   // [D]
    float*  Cvec  = (float*)(ws + 151007232);   // [D]
    float*  sumbuf= (float*)(ws + 151011328);   // [B] row sums
    float*  sqbuf = (float*)(ws + 151076864);   // [B] row sumsq

    prep_kernel<<<14368, 256, 0, stream>>>(
        x_u, x_m, wqkv1, bqkv1, wo1, bo1, wqkv2, bqkv2, wo2, bo2,
        lng, lnb, wproj, bproj,
        x_bf, wo12, wvT12, Wp, b12, Svec, Cvec, sumbuf);

    // W12[z] = wo12[z] @ wvT12[z]^T   (1024x1024, K=1024)
    gemm_w<<<dim3(16, 16, 2), 256, 0, stream>>>(
        wo12, wvT12, W12, DIM, DIM, DIM, DIM,
        (long)DIM * DIM, (long)DIM * DIM, (long)DIM * DIM);

    // z[:, z*D:(z+1)*D] = x_bf[z] @ W12[z]^T + b12[z]  (+ fused LN stats)
    gemm_bt2<1><<<dim3(64, 8, 2), 256, 0, stream>>>(
        x_bf, W12, zbuf, DIM, DIM, DIM, 2 * DIM,
        (long)BROWS * DIM, (long)DIM * DIM, (long)DIM,
        b12, nullptr, nullptr, sumbuf, sqbuf);

    // out = gelu(rstd*(z @ Wp^T - mu*S) + C)
    gemm_bt2<2><<<dim3(64, 8, 1), 256, 0, stream>>>(
        zbuf, Wp, d_out, 2 * DIM, 2 * DIM, 2 * DIM, DIM,
        0, 0, 0,
        nullptr, Svec, Cvec, sumbuf, sqbuf);
}

// Round 4
// 384.905 us; speedup vs baseline: 1.0468x; 1.0468x over previous
//
#include <hip/hip_runtime.h>
#include <cstdint>

// CrossAttentionFusion: seq_len=1 cross-attention => softmax==1 => attention is
// identity on V. Whole net collapses to:
//   W1 = w_o1 @ wv1 ; b1 = w_o1 @ bv1 + b_o1   (wv1 = w_qkv1[2d:3d,:])
//   z  = [x_u @ W1^T + b1 , x_m @ W2^T + b2]   [B, 2d]
//   out = gelu( LN(z; g,b) @ w_proj^T + b_proj )
// LN folded into proj epilogue: h = rstd*(z.Wp'^T - mu*S) + C.
// R6: R0/R3/R4/R5 all land 94-102us regardless of occupancy/prefetch/phase
// structure => per-K-tile FIXED cost (~2-2.5k cyc of barrier skew + drains +
// loop overhead) dominates, not any bandwidth. Lever: BK 32 -> 64 halves the
// number of sync points. 256x256 tile, 8 waves, 2-slot dbuf (128 KiB),
// distance-1 prefetch issued at tile start, vmcnt(0)+barrier once per 64-k.
// LDS swizzle generalized to 8 chunks: chunk c of row r stored at c^(r&7)
// (2 lanes per bank-group per 16-lane read => conflict-free).

#define DIM 1024
#define BROWS 16384

typedef __bf16 bf16x8 __attribute__((ext_vector_type(8)));
typedef float f32x4 __attribute__((ext_vector_type(4)));

__device__ __forceinline__ ushort f2bf(float f) {
    uint32_t u = __builtin_bit_cast(uint32_t, f);
    u = (u + 0x7fffu + ((u >> 16) & 1u)) >> 16;
    return (ushort)u;
}

// global -> LDS direct copy, 16B per lane. LDS dest is wave-uniform base;
// HW writes lane i at base + i*16.
__device__ __forceinline__ void async_copy16(const void* gsrc, void* ldst) {
    __builtin_amdgcn_global_load_lds(
        (__attribute__((address_space(1))) void*)((uintptr_t)gsrc),
        (__attribute__((address_space(3))) void*)((uint32_t)(uintptr_t)ldst),
        16, 0, 0);
}

// ---------------- merged prep kernel (unchanged) ----------------
__global__ __launch_bounds__(256) void prep_kernel(
        const float* __restrict__ x_u, const float* __restrict__ x_m,
        const float* __restrict__ wqkv1, const float* __restrict__ bqkv1,
        const float* __restrict__ wo1, const float* __restrict__ bo1,
        const float* __restrict__ wqkv2, const float* __restrict__ bqkv2,
        const float* __restrict__ wo2, const float* __restrict__ bo2,
        const float* __restrict__ lng, const float* __restrict__ lnb,
        const float* __restrict__ wproj, const float* __restrict__ bproj,
        ushort* __restrict__ x_bf, ushort* __restrict__ wo12,
        ushort* __restrict__ wvT12, ushort* __restrict__ Wp,
        float* __restrict__ b12, float* __restrict__ Svec, float* __restrict__ Cvec,
        float* __restrict__ sums) {
    const int b = blockIdx.x, t = threadIdx.x;
    __shared__ float red[4][4];
    __shared__ float tls[32][33];

    if (b < 8192) {
        const int n4 = (BROWS * DIM) / 4;
        int i = b * 256 + t;
        const int stride = 8192 * 256;
        const float4* xu4 = (const float4*)x_u;
        const float4* xm4 = (const float4*)x_m;
        ushort4* o4 = (ushort4*)x_bf;
#pragma unroll
        for (int it = 0; it < 4; it++, i += stride) {
            float4 v = (i < n4) ? xu4[i] : xm4[i - n4];
            ushort4 o;
            o.x = f2bf(v.x); o.y = f2bf(v.y); o.z = f2bf(v.z); o.w = f2bf(v.w);
            o4[i] = o;
        }
    } else if (b < 9216) {
        int j = b - 8192;
        float s1 = 0.f, s2 = 0.f, sS = 0.f, sC = 0.f;
        for (int c = t; c < DIM; c += 256) {
            s1 += wo1[j * DIM + c] * bqkv1[2 * DIM + c];
            s2 += wo2[j * DIM + c] * bqkv2[2 * DIM + c];
        }
        for (int c = t; c < 2 * DIM; c += 256) {
            float w = wproj[j * 2 * DIM + c];
            sS += w * lng[c];
            sC += w * lnb[c];
        }
        for (int o = 32; o; o >>= 1) {
            s1 += __shfl_down(s1, o, 64);
            s2 += __shfl_down(s2, o, 64);
            sS += __shfl_down(sS, o, 64);
            sC += __shfl_down(sC, o, 64);
        }
        int wid = t >> 6;
        if ((t & 63) == 0) { red[wid][0] = s1; red[wid][1] = s2; red[wid][2] = sS; red[wid][3] = sC; }
        __syncthreads();
        if (t == 0) {
            s1 = red[0][0] + red[1][0] + red[2][0] + red[3][0];
            s2 = red[0][1] + red[1][1] + red[2][1] + red[3][1];
            sS = red[0][2] + red[1][2] + red[2][2] + red[3][2];
            sC = red[0][3] + red[1][3] + red[2][3] + red[3][3];
            b12[j]       = s1 + bo1[j];
            b12[DIM + j] = s2 + bo2[j];
            Svec[j] = sS;
            Cvec[j] = sC + bproj[j];
        }
    } else if (b < 12288) {
        const int NWO = (DIM * DIM) / 4;
        const int NWP = (DIM * 2 * DIM) / 4;
        const int total = 2 * NWO + NWP;
        int i = (b - 9216) * 256 + t;
        const int stride = 3072 * 256;
        for (; i < total; i += stride) {
            if (i < 2 * NWO) {
                float4 v = (i < NWO) ? ((const float4*)wo1)[i] : ((const float4*)wo2)[i - NWO];
                ushort4 o;
                o.x = f2bf(v.x); o.y = f2bf(v.y); o.z = f2bf(v.z); o.w = f2bf(v.w);
                ((ushort4*)wo12)[i] = o;
            } else {
                int j = i - 2 * NWO;
                float4 v = ((const float4*)wproj)[j];
                int c = (j * 4) & (2 * DIM - 1);
                v.x *= lng[c]; v.y *= lng[c + 1]; v.z *= lng[c + 2]; v.w *= lng[c + 3];
                ushort4 o;
                o.x = f2bf(v.x); o.y = f2bf(v.y); o.z = f2bf(v.z); o.w = f2bf(v.w);
                ((ushort4*)Wp)[j] = o;
            }
        }
    } else if (b < 14336) {
        int tile = b - 12288;
        int z = tile >> 10;
        int t2 = tile & 1023;
        int mt = t2 >> 5, kt = t2 & 31;
        const float* src = z ? wqkv2 : wqkv1;
        int tr = t >> 3;
        int tc4 = (t & 7) * 4;
        const float* p = src + (long)(2 * DIM + mt * 32 + tr) * DIM + kt * 32 + tc4;
        float4 v = *(const float4*)p;
        tls[tr][tc4 + 0] = v.x; tls[tr][tc4 + 1] = v.y;
        tls[tr][tc4 + 2] = v.z; tls[tr][tc4 + 3] = v.w;
        __syncthreads();
        ushort4 o;
        o.x = f2bf(tls[tc4 + 0][tr]);
        o.y = f2bf(tls[tc4 + 1][tr]);
        o.z = f2bf(tls[tc4 + 2][tr]);
        o.w = f2bf(tls[tc4 + 3][tr]);
        *(ushort4*)(wvT12 + (long)z * DIM * DIM + (long)(kt * 32 + tr) * DIM + mt * 32 + tc4) = o;
    } else {
        int i = (b - 14336) * 256 + t;
        ((float4*)sums)[i] = float4{0.f, 0.f, 0.f, 0.f};
    }
}

// ---------------- small weight GEMM (64x64, unchanged) ----------
__global__ __launch_bounds__(256, 2) void gemm_w(
        const ushort* __restrict__ Ag, const ushort* __restrict__ Wg,
        ushort* __restrict__ Cg, int K, int lda, int ldw, int ldc,
        long sAz, long sWz, long sCz) {
    constexpr int BM = 64, BN = 64, BK = 32;
    constexpr int MT = BM / 32;
    constexpr int NT = BN / 32;
    __shared__ __align__(16) ushort As[BM * BK];
    __shared__ __align__(16) ushort Bs[BN * BK];
    const int tid = threadIdx.x;
    const int wid = tid >> 6;
    const int lane = tid & 63;
    const int quad = lane >> 4;
    const int l16 = lane & 15;
    const int waveM = wid >> 1, waveN = wid & 1;
    const int zb = blockIdx.z;

    const ushort* A = Ag + zb * sAz + (long)blockIdx.x * BM * lda;
    const ushort* W = Wg + zb * sWz + (long)blockIdx.y * BN * ldw;

    f32x4 acc[MT][NT] = {};
    constexpr int nA = (BM * BK) / (256 * 8);
    constexpr int nB = (BN * BK) / (256 * 8);
    const int swz = (l16 >> 1) & 3;
    const int rdA = quad ^ swz;
    for (int k0 = 0; k0 < K; k0 += BK) {
#pragma unroll
        for (int c = 0; c < nA; c++) {
            int idx = c * 256 + tid;
            int r = idx >> 2;
            int q = (idx & 3) ^ ((r >> 1) & 3);
            async_copy16(A + (long)r * lda + k0 + q * 8, (char*)As + (c * 256 + wid * 64) * 16);
        }
#pragma unroll
        for (int c = 0; c < nB; c++) {
            int idx = c * 256 + tid;
            int r = idx >> 2;
            int q = (idx & 3) ^ ((r >> 1) & 3);
            async_copy16(W + (long)r * ldw + k0 + q * 8, (char*)Bs + (c * 256 + wid * 64) * 16);
        }
        asm volatile("s_waitcnt vmcnt(0)" ::: "memory");
        __syncthreads();

        bf16x8 af[MT], bfg[NT];
#pragma unroll
        for (int im = 0; im < MT; im++)
            af[im] = *(const bf16x8*)(As + (waveM * (BM / 2) + im * 16 + l16) * BK + rdA * 8);
#pragma unroll
        for (int in = 0; in < NT; in++)
            bfg[in] = *(const bf16x8*)(Bs + (waveN * (BN / 2) + in * 16 + l16) * BK + rdA * 8);
#pragma unroll
        for (int im = 0; im < MT; im++)
#pragma unroll
            for (int in = 0; in < NT; in++)
                acc[im][in] = __builtin_amdgcn_mfma_f32_16x16x32_bf16(
                    af[im], bfg[in], acc[im][in], 0, 0, 0);
        __syncthreads();
    }

    const int gRow0 = blockIdx.x * BM + waveM * (BM / 2) + quad * 4;
    const int gCol0 = blockIdx.y * BN + waveN * (BN / 2) + l16;
    ushort* C = Cg + zb * sCz;
#pragma unroll
    for (int im = 0; im < MT; im++)
#pragma unroll
        for (int in = 0; in < NT; in++) {
            int col = gCol0 + in * 16;
#pragma unroll
            for (int r = 0; r < 4; r++) {
                int row = gRow0 + im * 16 + r;
                C[(long)row * ldc + col] = f2bf(acc[im][in][r]);
            }
        }
}

// ---------------- big GEMM: 256x256 tile, 8 waves, BK=64, 2-slot dbuf --------
// MODE 1: C bf16 = acc + bias[zb*DIM+col]; fused LN-stats atomics
// MODE 2: C fp32 = gelu(rstd*(acc - mu*S) + Cv)
//
// Schedule: per 64-k tile: [stage t+1 into slot (t+1)&1 FIRST] then 2 k-steps
// of {12 ds_read_b128 + 32 MFMA}, then vmcnt(0)+barrier once. The stage was
// issued a full tile (~3k cyc) before its drain => latency fully covered.
// Slot (t+1)&1 was last read by tile t-1, whose reads completed before the
// end-of-(t-1) barrier => no WAR hazard.
// LDS swizzle: chunk c of row r stored at position c^(r&7); stage source is
// pre-swizzled (linear dest, per global_load_lds requirement); reads apply the
// same XOR => for any 16-lane group each of 8 bank-groups gets exactly 2
// lanes (2-way = free, m136).
template <int MODE>
__global__ __launch_bounds__(512, 2) void gemm_bk64(
        const ushort* __restrict__ Ag, const ushort* __restrict__ Wg,
        void* __restrict__ Cg, int K, int lda, int ldw, int ldc,
        long sAz, long sWz, long sCz,
        const float* __restrict__ bias,
        const float* __restrict__ Svec, const float* __restrict__ Cvec,
        float* __restrict__ sumbuf, float* __restrict__ sqbuf) {
    __shared__ __align__(16) ushort As[2 * 16384];  // 2 slots x [256][64] bf16 = 64 KiB
    __shared__ __align__(16) ushort Bs[2 * 16384];  // 64 KiB
    const int tid = threadIdx.x;
    const int wid = tid >> 6;
    const int lane = tid & 63;
    const int quad = lane >> 4;
    const int l16 = lane & 15;
    const int waveM = wid >> 2;   // 0..1 -> 128 rows each
    const int waveN = wid & 3;    // 0..3 -> 64 cols each
    const int zb = blockIdx.z;

    const ushort* A = Ag + zb * sAz + (long)blockIdx.x * 256 * lda;
    const ushort* W = Wg + zb * sWz + (long)blockIdx.y * 256 * ldw;
    const int NTK = K >> 6;

    f32x4 acc[8][4] = {};

    // stage tile u (64-k) into slot s: 4 rounds A + 4 rounds B, 8 loads/thread
    auto stage = [&](int u, int s) {
        const int k0 = u << 6;
        char* sa = (char*)As + s * 32768;
        char* sb = (char*)Bs + s * 32768;
#pragma unroll
        for (int rnd = 0; rnd < 4; ++rnd) {
            int idx = rnd * 512 + tid;
            int r = idx >> 3;
            int q = (idx & 7) ^ (r & 7);
            async_copy16(A + (long)r * lda + k0 + q * 8, sa + (rnd * 512 + wid * 64) * 16);
        }
#pragma unroll
        for (int rnd = 0; rnd < 4; ++rnd) {
            int idx = rnd * 512 + tid;
            int r = idx >> 3;
            int q = (idx & 7) ^ (r & 7);
            async_copy16(W + (long)r * ldw + k0 + q * 8, sb + (rnd * 512 + wid * 64) * 16);
        }
    };

    // ---- prologue: stage tile 0 ----
    stage(0, 0);
    asm volatile("s_waitcnt vmcnt(0)" ::: "memory");
    __builtin_amdgcn_s_barrier();
    asm volatile("" ::: "memory");

    for (int t = 0; t < NTK; ++t) {
        const ushort* as = As + (t & 1) * 16384;
        const ushort* bs = Bs + (t & 1) * 16384;
        if (t + 1 < NTK) stage(t + 1, (t + 1) & 1);

#pragma unroll
        for (int ks = 0; ks < 2; ++ks) {
            bf16x8 af[8], bfg[4];
            const int rq = ((ks * 4 + quad) ^ (l16 & 7)) * 8;
#pragma unroll
            for (int j = 0; j < 4; ++j)
                bfg[j] = *(const bf16x8*)(bs + (waveN * 64 + j * 16 + l16) * 64 + rq);
#pragma unroll
            for (int i = 0; i < 8; ++i)
                af[i] = *(const bf16x8*)(as + (waveM * 128 + i * 16 + l16) * 64 + rq);
            __builtin_amdgcn_s_setprio(1);
#pragma unroll
            for (int i = 0; i < 8; ++i)
#pragma unroll
                for (int j = 0; j < 4; ++j)
                    acc[i][j] = __builtin_amdgcn_mfma_f32_16x16x32_bf16(
                        af[i], bfg[j], acc[i][j], 0, 0, 0);
            __builtin_amdgcn_s_setprio(0);
        }

        if (t + 1 < NTK) {
            asm volatile("s_waitcnt vmcnt(0)" ::: "memory");
            __builtin_amdgcn_s_barrier();
            asm volatile("" ::: "memory");
        }
    }

    // ---- epilogue: C/D layout col=lane&15, row=quad*4+reg ----
    const int gRow0 = blockIdx.x * 256 + waveM * 128 + quad * 4;
    const int gCol0 = blockIdx.y * 256 + waveN * 64 + l16;
    if constexpr (MODE == 1) {
        ushort* C = (ushort*)Cg + zb * sCz;
#pragma unroll
        for (int im = 0; im < 8; ++im) {
            float sr[4] = {0.f, 0.f, 0.f, 0.f};
            float qr[4] = {0.f, 0.f, 0.f, 0.f};
#pragma unroll
            for (int in = 0; in < 4; ++in) {
                int col = gCol0 + in * 16;
                float badd = bias[zb * DIM + col];
#pragma unroll
                for (int r = 0; r < 4; ++r) {
                    int row = gRow0 + im * 16 + r;
                    float val = acc[im][in][r] + badd;
                    C[(long)row * ldc + col] = f2bf(val);
                    sr[r] += val;
                    qr[r] += val * val;
                }
            }
#pragma unroll
            for (int r = 0; r < 4; ++r) {
                float s = sr[r], q = qr[r];
#pragma unroll
                for (int o = 1; o < 16; o <<= 1) {
                    s += __shfl_xor(s, o, 64);
                    q += __shfl_xor(q, o, 64);
                }
                if (l16 == 0) {
                    int row = gRow0 + im * 16 + r;
                    atomicAdd(&sumbuf[row], s);
                    atomicAdd(&sqbuf[row], q);
                }
            }
        }
    } else {
        float* O = (float*)Cg;
#pragma unroll
        for (int im = 0; im < 8; ++im) {
#pragma unroll
            for (int r = 0; r < 4; ++r) {
                int row = gRow0 + im * 16 + r;
                float sv = sumbuf[row], qv = sqbuf[row];
                float m = sv * (1.f / 2048.f);
                float var = qv * (1.f / 2048.f) - m * m;
                float rstd = rsqrtf(var + 1e-5f);
#pragma unroll
                for (int in = 0; in < 4; ++in) {
                    int col = gCol0 + in * 16;
                    float h = rstd * (acc[im][in][r] - m * Svec[col]) + Cvec[col];
                    O[(long)row * ldc + col] = 0.5f * h * (1.0f + erff(h * 0.7071067811865475f));
                }
            }
        }
    }
}

// ---------------- launch ----------------

extern "C" void kernel_launch(void* const* d_in, const int* in_sizes, int n_in,
                              void* d_out, int out_size, void* d_ws, size_t ws_size,
                              hipStream_t stream) {
    (void)in_sizes; (void)n_in; (void)out_size; (void)ws_size;
    const float* x_u   = (const float*)d_in[0];
    const float* x_m   = (const float*)d_in[1];
    const float* wqkv1 = (const float*)d_in[2];
    const float* bqkv1 = (const float*)d_in[3];
    const float* wo1   = (const float*)d_in[4];
    const float* bo1   = (const float*)d_in[5];
    const float* wqkv2 = (const float*)d_in[6];
    const float* bqkv2 = (const float*)d_in[7];
    const float* wo2   = (const float*)d_in[8];
    const float* bo2   = (const float*)d_in[9];
    const float* lng   = (const float*)d_in[10];
    const float* lnb   = (const float*)d_in[11];
    const float* wproj = (const float*)d_in[12];
    const float* bproj = (const float*)d_in[13];

    char* ws = (char*)d_ws;
    ushort* x_bf  = (ushort*)(ws + 0);          // [2][B][D] bf16: 67,108,864 B
    ushort* wo12  = (ushort*)(ws + 67108864);   // [2][D][D]: 4 MB
    ushort* wvT12 = (ushort*)(ws + 71303168);   // [2][D][D]: 4 MB
    ushort* W12   = (ushort*)(ws + 75497472);   // [2][D][D]: 4 MB
    ushort* Wp    = (ushort*)(ws + 79691776);   // [D][2D]: 4 MB
    ushort* zbuf  = (ushort*)(ws + 83886080);   // [B][2D]: 67,108,864 B
    float*  b12   = (float*)(ws + 150994944);   // [2][D]
    float*  Svec  = (float*)(ws + 151003136);   // [D]
    float*  Cvec  = (float*)(ws + 151007232);   // [D]
    float*  sumbuf= (float*)(ws + 151011328);   // [B] row sums
    float*  sqbuf = (float*)(ws + 151076864);   // [B] row sumsq

    prep_kernel<<<14368, 256, 0, stream>>>(
        x_u, x_m, wqkv1, bqkv1, wo1, bo1, wqkv2, bqkv2, wo2, bo2,
        lng, lnb, wproj, bproj,
        x_bf, wo12, wvT12, Wp, b12, Svec, Cvec, sumbuf);

    // W12[z] = wo12[z] @ wvT12[z]^T   (1024x1024, K=1024)
    gemm_w<<<dim3(16, 16, 2), 256, 0, stream>>>(
        wo12, wvT12, W12, DIM, DIM, DIM, DIM,
        (long)DIM * DIM, (long)DIM * DIM, (long)DIM * DIM);

    // z[:, z*D:(z+1)*D] = x_bf[z] @ W12[z]^T + b12[z]  (+ fused LN stats)
    gemm_bk64<1><<<dim3(64, 4, 2), 512, 0, stream>>>(
        x_bf, W12, zbuf, DIM, DIM, DIM, 2 * DIM,
        (long)BROWS * DIM, (long)DIM * DIM, (long)DIM,
        b12, nullptr, nullptr, sumbuf, sqbuf);

    // out = gelu(rstd*(z @ Wp^T - mu*S) + C)
    gemm_bk64<2><<<dim3(64, 4, 1), 512, 0, stream>>>(
        zbuf, Wp, d_out, 2 * DIM, 2 * DIM, 2 * DIM, DIM,
        0, 0, 0,
        nullptr, Svec, Cvec, sumbuf, sqbuf);
}